// Round 4
// baseline (306.176 us; speedup 1.0000x reference)
//
#include <hip/hip_runtime.h>
#include <hip/hip_bf16.h>
#include <stdint.h>

#define NNODE   17
#define FDIM    64
#define GPB     8                   // graphs per chunk
#define ROWS    (GPB*NNODE)         // 136
#define LROWS   144                 // padded to 9 full 16-row MFMA tiles
#define LDK     132                 // padded K stride in bf16 elems (264B rows: measured conflict-free)
#define NT      9                   // row-tiles (last half-masked)
#define NBLOCK  1024
#define ITERS   8                   // 1024*8*8 = 65536 graphs

typedef __attribute__((ext_vector_type(8))) short short8;
typedef __attribute__((ext_vector_type(4))) float f32x4;

// LDS 39.4 KB + VGPR<=128 (__launch_bounds__ 256,4) -> 4 blocks/CU
__global__ __launch_bounds__(256, 4) void egc_kernel(
    const float* __restrict__ x, const float* __restrict__ adj,
    const float* __restrict__ wself, const float* __restrict__ wneigh,
    const float* __restrict__ bias, float* __restrict__ out)
{
    __shared__ uint16_t sXZ[LROWS][LDK];      // 38016 B
    __shared__ float sAdj[NNODE * NNODE];
    __shared__ float sBias[FDIM];

    const int t    = threadIdx.x;
    const int lane = t & 63;
    const int wv   = t >> 6;          // wave id == output col-tile (16 cols each)
    const int lr   = lane & 15;
    const int lh   = lane >> 4;

    // ---- once per block: stage W2T[o][k] (k<64: Ws[k][o], k>=64: Wn[k-64][o])
    for (int idx = t; idx < FDIM * 128; idx += 256) {
        int o = idx >> 7, k = idx & 127;
        float v = (k < 64) ? wself[k * 64 + o] : wneigh[(k - 64) * 64 + o];
        __hip_bfloat16 b = __float2bfloat16(v);
        sXZ[o][k] = *(uint16_t*)&b;
    }
    for (int i = t; i < NNODE * NNODE; i += 256) sAdj[i] = adj[i];
    if (t < FDIM) sBias[t] = bias[t];
    for (int i = t; i < (LROWS - ROWS) * LDK; i += 256) {   // zero pad rows
        int r = i / LDK, c = i % LDK;
        sXZ[ROWS + r][c] = 0;
    }
    __syncthreads();

    // W-frags: lane l holds W2T[o=16*wv+lr][k=32q+8*lh+e]  (MFMA A-operand after swap)
    short8 wfrag[4];
    #pragma unroll
    for (int q = 0; q < 4; ++q)
        wfrag[q] = *(const short8*)&sXZ[16 * wv + lr][32 * q + 8 * lh];
    const float breg = sBias[16 * wv + 4 * lh];   // D rows = features 4*lh+r (per-reg bias added below)
    float bias4[4];
    #pragma unroll
    for (int r = 0; r < 4; ++r) bias4[r] = sBias[16 * wv + 4 * lh + r];
    (void)breg;
    __syncthreads();

    // ---- T14 prefetch state: 9 float4 per thread (threads >=128 use only 8)
    float4 pf[9];
    const size_t cbase = (size_t)blockIdx.x * ITERS;

    auto issue_loads = [&](size_t chunk) {
        const float4* xg = (const float4*)(x + chunk * (size_t)(ROWS * FDIM));
        #pragma unroll
        for (int j = 0; j < 8; ++j) pf[j] = xg[t + j * 256];
        if (t < 128) pf[8] = xg[t + 2048];
    };

    issue_loads(cbase);

    for (int it = 0; it < ITERS; ++it) {
        // ---- P1: regs -> bf16 LDS cols 0..63 (cvt_pk + b64 writes)
        #pragma unroll
        for (int j = 0; j < 9; ++j) {
            if (j < 8 || t < 128) {
                int idx = t + j * 256;
                int row = idx >> 4, c4 = (idx & 15) << 2;
                float4 v = pf[j];
                __hip_bfloat162 lo = __float22bfloat162_rn(make_float2(v.x, v.y));
                __hip_bfloat162 hi = __float22bfloat162_rn(make_float2(v.z, v.w));
                uint2 pk;
                pk.x = *(uint32_t*)&lo;
                pk.y = *(uint32_t*)&hi;
                *(uint2*)&sXZ[row][c4] = pk;
            }
        }
        __syncthreads();

        // prefetch next chunk while P2/P3 compute
        if (it + 1 < ITERS) issue_loads(cbase + it + 1);

        // ---- P2: z[g,n,i] = sum_m adj[n,m]*x[g,m,i] -> bf16 LDS cols 64..127
        {
            const int i2 = (t & 31) << 1;         // feature pair base
            const int g  = t >> 5;                // graph 0..7
            float xa[NNODE], xb[NNODE];
            #pragma unroll
            for (int m = 0; m < NNODE; ++m) {
                uint32_t p = *(const uint32_t*)&sXZ[g * NNODE + m][i2];
                xa[m] = __uint_as_float(p << 16);
                xb[m] = __uint_as_float(p & 0xffff0000u);
            }
            #pragma unroll 1
            for (int n = 0; n < NNODE; ++n) {
                float a0 = 0.f, a1 = 0.f;
                #pragma unroll
                for (int m = 0; m < NNODE; ++m) {
                    float w = sAdj[n * NNODE + m];
                    a0 += w * xa[m]; a1 += w * xb[m];
                }
                __hip_bfloat162 zz = __float22bfloat162_rn(make_float2(a0, a1));
                *(uint32_t*)&sXZ[g * NNODE + n][64 + i2] = *(uint32_t*)&zz;
            }
        }
        __syncthreads();

        // ---- P3: out^T-layout MFMA: D = W2T-frag x XZ-frag -> lane stores float4
        {
            float* outg = out + (cbase + it) * (size_t)(ROWS * FDIM);
            #pragma unroll 3
            for (int rt = 0; rt < NT; ++rt) {
                f32x4 acc = { bias4[0], bias4[1], bias4[2], bias4[3] };
                #pragma unroll
                for (int q = 0; q < 4; ++q) {
                    // B'-frag: lane l holds XZ[row=rt*16+lr][k=32q+8*lh+e]
                    short8 af = *(const short8*)&sXZ[rt * 16 + lr][32 * q + 8 * lh];
                    acc = __builtin_amdgcn_mfma_f32_16x16x32_bf16(wfrag[q], af, acc, 0, 0, 0);
                }
                // D[row=feature 4*lh+r][col=XZ-row lr] -> float4 store
                const int orow = rt * 16 + lr;
                if (orow < ROWS)
                    *(float4*)&outg[orow * 64 + 16 * wv + 4 * lh] =
                        *(float4*)&acc;
            }
        }
        __syncthreads();
    }
}

extern "C" void kernel_launch(void* const* d_in, const int* in_sizes, int n_in,
                              void* d_out, int out_size, void* d_ws, size_t ws_size,
                              hipStream_t stream) {
    (void)in_sizes; (void)n_in; (void)d_ws; (void)ws_size; (void)out_size;
    const float* x      = (const float*)d_in[0];
    const float* adj    = (const float*)d_in[1];
    const float* wself  = (const float*)d_in[2];
    const float* wneigh = (const float*)d_in[3];
    const float* bias   = (const float*)d_in[4];
    float* out = (float*)d_out;
    egc_kernel<<<NBLOCK, 256, 0, stream>>>(x, adj, wself, wneigh, bias, out);
}

// Round 6
// 134.247 us; speedup vs baseline: 2.2807x; 2.2807x over previous
//
#include <hip/hip_runtime.h>
#include <stdint.h>

#define NNODE 17
#define FDIM  64
#define GPB   8
#define ROWS  (GPB*NNODE)       // 136
#define LDK   132               // sXZ row stride (264 B: b64-aligned, 2-way banks = free)
#define LDT   204               // sXT row stride (408 B: b64-aligned, 2-way banks = free)
#define GSTR  24                // per-graph col base in sXT (16B-aligned)
#define NBLOCK 512
#define ITERS  16               // 512*16*8 = 65536 graphs

typedef __attribute__((ext_vector_type(4)))  short short4v;
typedef __attribute__((ext_vector_type(8)))  short short8v;
typedef __attribute__((ext_vector_type(16))) float f32x16;

__device__ __forceinline__ uint32_t bf16b(float f) {
    uint32_t u = __float_as_uint(f);
    return (u + 0x7fffu + ((u >> 16) & 1u)) >> 16;   // RNE
}
__device__ __forceinline__ uint32_t bfpack(float lo, float hi) {
    return bf16b(lo) | (bf16b(hi) << 16);
}
__device__ __forceinline__ short8v ld8(const uint16_t* p) {   // 2x ds_read_b64
    short4v lo = *(const short4v*)p;
    short4v hi = *(const short4v*)(p + 4);
    return __builtin_shufflevector(lo, hi, 0, 1, 2, 3, 4, 5, 6, 7);
}

// LDS ~68 KB -> 2 blocks/CU; launch_bounds(256,2) -> VGPR budget 256 (no spill for pf[9])
__global__ __launch_bounds__(256, 2) void egc_kernel(
    const float* __restrict__ x, const float* __restrict__ adj,
    const float* __restrict__ wself, const float* __restrict__ wneigh,
    const float* __restrict__ bias, float* __restrict__ out)
{
    __shared__ uint16_t sXZ[160][LDK];      // rows 0..135 = [x(64)|z(64)]; 136..159 zeroed pad
    __shared__ uint16_t sXT[FDIM][LDT];     // x transposed: [feat][GSTR*g + node]; pads zeroed
    __shared__ float sAdj[NNODE * NNODE];
    __shared__ float sBias[FDIM];

    const int t  = threadIdx.x;
    const int l  = t & 63;
    const int wv = t >> 6;
    const int n_ = l & 31;      // lane-low: A.m / B.n / D.n
    const int h_ = l >> 5;      // lane-half: k-half select / D-row +4

    // ---- once: zero LDS regions that feed MFMA but are not (re)written every iter.
    // sXT pad cols (node 17..23 per graph, tail cols) held NaN-pattern garbage:
    // NaN * 0-weight = NaN poisoned P2's accumulator in R5. Zero it all once.
    for (int i = t; i < FDIM * LDT; i += 256) ((uint16_t*)sXT)[i] = 0;
    for (int i = t; i < 24 * LDK; i += 256) ((uint16_t*)&sXZ[136][0])[i] = 0;

    // ---- once: stage W2T[o][k] (k<64: Ws[k][o] else Wn[k-64][o]) into sXZ rows 0..63
    for (int idx = t; idx < FDIM * 128; idx += 256) {
        int o = idx >> 7, k = idx & 127;
        float v = (k < 64) ? wself[k * 64 + o] : wneigh[(k - 64) * 64 + o];
        sXZ[o][k] = (uint16_t)bf16b(v);
    }
    for (int i = t; i < NNODE * NNODE; i += 256) sAdj[i] = adj[i];
    if (t < FDIM) sBias[t] = bias[t];
    __syncthreads();

    // per-wave output col-half; W B-frags: B[k=16ks+8h+e][n=feat 32ctw+n_]
    const int ctw = wv & 1;
    short8v wfrag[8];
    #pragma unroll
    for (int ks = 0; ks < 8; ++ks)
        wfrag[ks] = ld8(&sXZ[32 * ctw + n_][16 * ks + 8 * h_]);
    const float breg = sBias[32 * ctw + n_];

    // z-GEMM B-frags: B[k=in-node][n=out-node] = adj[n][k], zero-padded k>=17 / n>=17
    short8v zb[2];
    #pragma unroll
    for (int ks = 0; ks < 2; ++ks) {
        short8v v;
        #pragma unroll
        for (int e = 0; e < 8; ++e) {
            int k = 16 * ks + 8 * h_ + e;
            float a = (k < NNODE && n_ < NNODE) ? sAdj[n_ * NNODE + k] : 0.f;
            v[e] = (short)bf16b(a);
        }
        zb[ks] = v;
    }
    __syncthreads();

    float4 pf[9];
    const size_t cbase = (size_t)blockIdx.x * ITERS;
    const float4* xg0 = (const float4*)x;
    {
        const float4* xg = xg0 + cbase * (ROWS * 16);
        #pragma unroll
        for (int j = 0; j < 8; ++j) pf[j] = xg[t + j * 256];
        if (t < 128) pf[8] = xg[t + 2048];
    }

    for (int it = 0; it < ITERS; ++it) {
        // ---- P1: pf -> sXZ x-cols (b64) + sXT transposed (4x u16)
        #pragma unroll
        for (int j = 0; j < 9; ++j) {
            if (j < 8 || t < 128) {
                int idx = t + j * 256;
                int row = idx >> 4, c4 = (idx & 15) << 2;
                int g = row / NNODE;            // magic-mul
                int tc = GSTR * g + (row - g * NNODE);
                float4 v = pf[j];
                uint2 pk; pk.x = bfpack(v.x, v.y); pk.y = bfpack(v.z, v.w);
                *(uint2*)&sXZ[row][c4] = pk;
                sXT[c4 + 0][tc] = (uint16_t)(pk.x & 0xffff);
                sXT[c4 + 1][tc] = (uint16_t)(pk.x >> 16);
                sXT[c4 + 2][tc] = (uint16_t)(pk.y & 0xffff);
                sXT[c4 + 3][tc] = (uint16_t)(pk.y >> 16);
            }
        }
        __syncthreads();

        // prefetch next chunk (covered by P2+P3 compute; VGPR budget holds it)
        if (it + 1 < ITERS) {
            const float4* xg = xg0 + (cbase + it + 1) * (ROWS * 16);
            #pragma unroll
            for (int j = 0; j < 8; ++j) pf[j] = xg[t + j * 256];
            if (t < 128) pf[8] = xg[t + 2048];
        }

        // ---- P2: z^T[feat][node] = x^T * adjPad on MFMA pipe; 16 units (8g x 2mt) / 4 waves
        #pragma unroll
        for (int uu = 0; uu < 4; ++uu) {
            int u = wv * 4 + uu;
            int g = u >> 1, mt = u & 1;
            f32x16 zacc;
            #pragma unroll
            for (int r = 0; r < 16; ++r) zacc[r] = 0.f;
            #pragma unroll
            for (int ks = 0; ks < 2; ++ks) {
                // A[m=feat 32mt+n_][k=node 16ks+8h+e]; pad nodes zeroed both sides now
                short8v a = ld8(&sXT[32 * mt + n_][GSTR * g + 16 * ks + 8 * h_]);
                zacc = __builtin_amdgcn_mfma_f32_32x32x16_bf16(a, zb[ks], zacc, 0, 0, 0);
            }
            // D[m=feat (r&3)+8(r>>2)+4h+32mt][n=node n_] -> sXZ z-cols, b64 writes
            if (n_ < NNODE) {
                uint16_t* zrow = &sXZ[g * NNODE + n_][64 + 32 * mt + 4 * h_];
                #pragma unroll
                for (int q = 0; q < 4; ++q) {
                    uint2 pk;
                    pk.x = bfpack(zacc[4 * q + 0], zacc[4 * q + 1]);
                    pk.y = bfpack(zacc[4 * q + 2], zacc[4 * q + 3]);
                    *(uint2*)&zrow[8 * q] = pk;
                }
            }
        }
        __syncthreads();

        // ---- P3: out = XZ @ [Ws;Wn] + bias; D cols = 32 feats -> full 128B-line stores
        {
            float* outg = out + (cbase + it) * (size_t)(ROWS * FDIM);
            #pragma unroll
            for (int ri = 0; ri < 3; ++ri) {
                int rt = (wv >> 1) + 2 * ri;     // waves0,1: rt 0,2,4 ; waves2,3: rt 1,3
                if (rt < 5) {
                    f32x16 acc;
                    #pragma unroll
                    for (int r = 0; r < 16; ++r) acc[r] = breg;
                    #pragma unroll
                    for (int ks = 0; ks < 8; ++ks) {
                        // A[m=XZrow 32rt+n_][k=16ks+8h+e]
                        short8v a = ld8(&sXZ[32 * rt + n_][16 * ks + 8 * h_]);
                        acc = __builtin_amdgcn_mfma_f32_32x32x16_bf16(a, wfrag[ks], acc, 0, 0, 0);
                    }
                    // D[m=row (r&3)+8(r>>2)+4h][n=feat 32ctw+n_]: 32-lane rows = full lines
                    #pragma unroll
                    for (int r = 0; r < 16; ++r) {
                        int row = 32 * rt + (r & 3) + 8 * (r >> 2) + 4 * h_;
                        if (rt < 4 || r < 4)     // rt==4: only rows 128..135 valid
                            outg[row * 64 + 32 * ctw + n_] = acc[r];
                    }
                }
            }
        }
        __syncthreads();
    }
}

extern "C" void kernel_launch(void* const* d_in, const int* in_sizes, int n_in,
                              void* d_out, int out_size, void* d_ws, size_t ws_size,
                              hipStream_t stream) {
    (void)in_sizes; (void)n_in; (void)d_ws; (void)ws_size; (void)out_size;
    const float* x      = (const float*)d_in[0];
    const float* adj    = (const float*)d_in[1];
    const float* wself  = (const float*)d_in[2];
    const float* wneigh = (const float*)d_in[3];
    const float* bias   = (const float*)d_in[4];
    float* out = (float*)d_out;
    egc_kernel<<<NBLOCK, 256, 0, stream>>>(x, adj, wself, wneigh, bias, out);
}

// Round 7
// 134.109 us; speedup vs baseline: 2.2830x; 1.0010x over previous
//
#include <hip/hip_runtime.h>
#include <stdint.h>

#define NNODE 17
#define FDIM  64
#define GPB   8
#define ROWS  (GPB*NNODE)       // 136
#define LDK   132               // sXZ row stride (264 B: b64-aligned, measured conflict-free)
#define NBLOCK 512
#define ITERS  16               // 512*16*8 = 65536 graphs

typedef __attribute__((ext_vector_type(4)))  short short4v;
typedef __attribute__((ext_vector_type(8)))  short short8v;
typedef __attribute__((ext_vector_type(16))) float f32x16;

__device__ __forceinline__ uint32_t bf16b(float f) {
    uint32_t u = __float_as_uint(f);
    return (u + 0x7fffu + ((u >> 16) & 1u)) >> 16;   // RNE
}
__device__ __forceinline__ uint32_t bfpack(float lo, float hi) {
    return bf16b(lo) | (bf16b(hi) << 16);
}
__device__ __forceinline__ short8v ld8(const uint16_t* p) {   // 2x ds_read_b64
    short4v lo = *(const short4v*)p;
    short4v hi = *(const short4v*)(p + 4);
    return __builtin_shufflevector(lo, hi, 0, 1, 2, 3, 4, 5, 6, 7);
}

// LDS ~44 KB -> 3 blocks/CU (12 waves/CU); VGPR budget 170 via launch_bounds(256,3)
__global__ __launch_bounds__(256, 3) void egc_kernel(
    const float* __restrict__ x, const float* __restrict__ adj,
    const float* __restrict__ wself, const float* __restrict__ wneigh,
    const float* __restrict__ bias, float* __restrict__ out)
{
    __shared__ uint16_t sXZ[160][LDK];      // rows 0..135 = [x(64)|z(64)]; 136..159 zeroed pad
    __shared__ float sAdj[NNODE * NNODE];
    __shared__ float sBias[FDIM];

    const int t  = threadIdx.x;
    const int l  = t & 63;
    const int wv = t >> 6;
    const int n_ = l & 31;      // lane-low: A.m / B.n / D.n
    const int h_ = l >> 5;      // lane-half: k-half select / D-row +4

    // ---- once: zero pad rows 136..159 (read by P2 k-pad gather and P3 rt4; NaN-hygiene)
    for (int i = t; i < 24 * LDK; i += 256) ((uint16_t*)&sXZ[136][0])[i] = 0;

    // ---- once: stage W2T[o][k] (k<64: Ws[k][o] else Wn[k-64][o]) into sXZ rows 0..63
    for (int idx = t; idx < FDIM * 128; idx += 256) {
        int o = idx >> 7, k = idx & 127;
        float v = (k < 64) ? wself[k * 64 + o] : wneigh[(k - 64) * 64 + o];
        sXZ[o][k] = (uint16_t)bf16b(v);
    }
    for (int i = t; i < NNODE * NNODE; i += 256) sAdj[i] = adj[i];
    if (t < FDIM) sBias[t] = bias[t];
    __syncthreads();

    // per-wave output col-half; W B-frags: B[k=16ks+8h+e][n=feat 32ctw+n_]
    const int ctw = wv & 1;
    short8v wfrag[8];
    #pragma unroll
    for (int ks = 0; ks < 8; ++ks)
        wfrag[ks] = ld8(&sXZ[32 * ctw + n_][16 * ks + 8 * h_]);
    const float breg = sBias[32 * ctw + n_];

    // z-GEMM B-frags: B[k=in-node][n=out-node] = adj[n][k], zero-padded k>=17 / n>=17
    short8v zb[2];
    #pragma unroll
    for (int ks = 0; ks < 2; ++ks) {
        short8v v;
        #pragma unroll
        for (int e = 0; e < 8; ++e) {
            int k = 16 * ks + 8 * h_ + e;
            float a = (k < NNODE && n_ < NNODE) ? sAdj[n_ * NNODE + k] : 0.f;
            v[e] = (short)bf16b(a);
        }
        zb[ks] = v;
    }
    __syncthreads();

    float4 pf[9];
    const size_t cbase = (size_t)blockIdx.x * ITERS;
    const float4* xg0 = (const float4*)x;
    {
        const float4* xg = xg0 + cbase * (ROWS * 16);
        #pragma unroll
        for (int j = 0; j < 8; ++j) pf[j] = xg[t + j * 256];
        if (t < 128) pf[8] = xg[t + 2048];
    }

    for (int it = 0; it < ITERS; ++it) {
        // ---- P1: pf -> sXZ x-cols (9 b64 writes; sXT eliminated)
        #pragma unroll
        for (int j = 0; j < 9; ++j) {
            if (j < 8 || t < 128) {
                int idx = t + j * 256;
                int row = idx >> 4, c4 = (idx & 15) << 2;
                float4 v = pf[j];
                uint2 pk; pk.x = bfpack(v.x, v.y); pk.y = bfpack(v.z, v.w);
                *(uint2*)&sXZ[row][c4] = pk;
            }
        }
        __syncthreads();

        // prefetch next chunk (in flight during P2+P3)
        if (it + 1 < ITERS) {
            const float4* xg = xg0 + (cbase + it + 1) * (ROWS * 16);
            #pragma unroll
            for (int j = 0; j < 8; ++j) pf[j] = xg[t + j * 256];
            if (t < 128) pf[8] = xg[t + 2048];
        }

        // ---- P2: z^T[feat][node] = x^T @ adjPad^T on MFMA; 16 units (8g x 2mt) / 4 waves
        #pragma unroll
        for (int uu = 0; uu < 4; ++uu) {
            int u = wv * 4 + uu;
            int g = u >> 1, mt = u & 1;
            f32x16 zacc;
            #pragma unroll
            for (int r = 0; r < 16; ++r) zacc[r] = 0.f;
            #pragma unroll
            for (int ks = 0; ks < 2; ++ks) {
                // A[m=feat 32mt+n_][k=node 16ks+8h_+e] = sXZ[g*17+k][32mt+n_]
                // 8 strided u16 reads; rows beyond node 16 hit next graph / zeroed pad,
                // killed by zb's zero B-weights (real numbers x 0 = 0, no NaN).
                const uint16_t* base = &sXZ[g * NNODE + 16 * ks + 8 * h_][32 * mt + n_];
                short8v a;
                #pragma unroll
                for (int e = 0; e < 8; ++e) a[e] = (short)base[e * LDK];
                zacc = __builtin_amdgcn_mfma_f32_32x32x16_bf16(a, zb[ks], zacc, 0, 0, 0);
            }
            // D[m=feat (r&3)+8(r>>2)+4h+32mt][n=node n_] -> sXZ z-cols, 4x b64
            if (n_ < NNODE) {
                uint16_t* zrow = &sXZ[g * NNODE + n_][64 + 32 * mt + 4 * h_];
                #pragma unroll
                for (int q = 0; q < 4; ++q) {
                    uint2 pk;
                    pk.x = bfpack(zacc[4 * q + 0], zacc[4 * q + 1]);
                    pk.y = bfpack(zacc[4 * q + 2], zacc[4 * q + 3]);
                    *(uint2*)&zrow[8 * q] = pk;
                }
            }
        }
        __syncthreads();

        // ---- P3: out = XZ @ [Ws;Wn] + bias; D cols = 32 feats -> full 128B-line stores
        {
            float* outg = out + (cbase + it) * (size_t)(ROWS * FDIM);
            #pragma unroll
            for (int ri = 0; ri < 3; ++ri) {
                int rt = (wv >> 1) + 2 * ri;     // waves0,1: rt 0,2,4 ; waves2,3: rt 1,3
                if (rt < 5) {
                    f32x16 acc;
                    #pragma unroll
                    for (int r = 0; r < 16; ++r) acc[r] = breg;
                    #pragma unroll
                    for (int ks = 0; ks < 8; ++ks) {
                        short8v a = ld8(&sXZ[32 * rt + n_][16 * ks + 8 * h_]);
                        acc = __builtin_amdgcn_mfma_f32_32x32x16_bf16(a, wfrag[ks], acc, 0, 0, 0);
                    }
                    #pragma unroll
                    for (int r = 0; r < 16; ++r) {
                        int row = 32 * rt + (r & 3) + 8 * (r >> 2) + 4 * h_;
                        if (rt < 4 || r < 4)     // rt==4: only rows 128..135 valid
                            outg[row * 64 + 32 * ctw + n_] = acc[r];
                    }
                }
            }
        }
        __syncthreads();
    }
}

extern "C" void kernel_launch(void* const* d_in, const int* in_sizes, int n_in,
                              void* d_out, int out_size, void* d_ws, size_t ws_size,
                              hipStream_t stream) {
    (void)in_sizes; (void)n_in; (void)d_ws; (void)ws_size; (void)out_size;
    const float* x      = (const float*)d_in[0];
    const float* adj    = (const float*)d_in[1];
    const float* wself  = (const float*)d_in[2];
    const float* wneigh = (const float*)d_in[3];
    const float* bias   = (const float*)d_in[4];
    float* out = (float*)d_out;
    egc_kernel<<<NBLOCK, 256, 0, stream>>>(x, adj, wself, wneigh, bias, out);
}